// Round 4
// baseline (390.525 us; speedup 1.0000x reference)
//
#include <hip/hip_runtime.h>
#include <hip/hip_bf16.h>

typedef __attribute__((ext_vector_type(8))) short short8;
typedef __attribute__((ext_vector_type(4))) float float4v;

#define N_NODES 131072
#define E_EDGES 256
#define IN_CH   128
#define OUT_CH  256
#define NBLK    512          // 2 blocks/CU x 256 CUs -> co-resident by capacity
#define NPB     256          // nodes per block
#define TPB     4            // 64-row GEMM tiles per block

// ---------------------------------------------------------------------------
// Fused kernel, occupancy-rebalanced (R3 post-mortem: 8 waves/CU was the
// bottleneck -- Occupancy 22.6%, VALUBusy 11%, hbm 14%: latency-bound).
// Now 512-thread blocks (8 waves), 2 blocks/CU = 16 waves/CU, with the
// per-wave GEMM fragment shrunk 4x4 -> 4x2 (acc 32 + bfrag 32 regs) so the
// whole kernel fits the 128-VGPR cap of 4 waves/SIMD.
// Correctness machinery identical to the R3 PASS: plain launch (graph-safe),
// atomic arrive/spin grid barrier with timeout->local-recompute fallback,
// gram via device-scope atomicOr + agent-scope reload. Masks stay in LDS.
// ---------------------------------------------------------------------------
__global__ __launch_bounds__(512, 4) void k_fused(
    const float* __restrict__ H, const float* __restrict__ U,
    const float* __restrict__ W, const float* __restrict__ bias,
    unsigned* __restrict__ gram, unsigned* __restrict__ bar,
    float* __restrict__ out) {
  __shared__ __hip_bfloat16 A[64 * 136];       // 17408 B (136: bank de-alias)
  __shared__ unsigned gsh[E_EDGES * 8];        //  8192 B
  __shared__ unsigned long long msh[NPB * 4];  //  8192 B
  __shared__ float ssh[64];
  __shared__ float bsh[OUT_CH];
  __shared__ int fb_sh;

  const int tid = threadIdx.x;
  const int wave = tid >> 6, lane = tid & 63;
  const int quad = lane >> 4, c16 = lane & 15;

  // ---- phase A: masks + gram pattern, 8 waves x 32 nodes ----
  const int nbase = blockIdx.x * NPB + wave * 32;
  unsigned r[4][8];
#pragma unroll
  for (int g = 0; g < 4; ++g)
#pragma unroll
    for (int j = 0; j < 8; ++j) r[g][j] = 0u;

  for (int it = 0; it < 8; ++it) {  // 4 nodes/iter -> 16 loads in flight
    const int n0 = nbase + it * 4;
    float v[4][4];
#pragma unroll
    for (int q = 0; q < 4; ++q) {
      const float* row = H + (size_t)(n0 + q) * E_EDGES;
#pragma unroll
      for (int g = 0; g < 4; ++g) v[q][g] = row[lane + g * 64];
    }
#pragma unroll
    for (int q = 0; q < 4; ++q) {
      unsigned long long b0 = __ballot(v[q][0] >= 0.5f);
      unsigned long long b1 = __ballot(v[q][1] >= 0.5f);
      unsigned long long b2 = __ballot(v[q][2] >= 0.5f);
      unsigned long long b3 = __ballot(v[q][3] >= 0.5f);
      if (lane < 4)
        msh[(size_t)(wave * 32 + it * 4 + q) * 4 + lane] =
            (lane == 0) ? b0 : (lane == 1) ? b1 : (lane == 2) ? b2 : b3;
      unsigned w[8] = {(unsigned)b0, (unsigned)(b0 >> 32),
                       (unsigned)b1, (unsigned)(b1 >> 32),
                       (unsigned)b2, (unsigned)(b2 >> 32),
                       (unsigned)b3, (unsigned)(b3 >> 32)};
      const unsigned long long bb[4] = {b0, b1, b2, b3};
#pragma unroll
      for (int g = 0; g < 4; ++g) {
        const unsigned sel = ((unsigned)(bb[g] >> lane) & 1u) ? 0xFFFFFFFFu : 0u;
#pragma unroll
        for (int j = 0; j < 8; ++j) r[g][j] |= w[j] & sel;
      }
    }
  }

  // LDS merge of the 8 waves' gram contributions, then global atomicOr.
  for (int i = tid; i < E_EDGES * 8; i += 512) gsh[i] = 0u;
  __syncthreads();
#pragma unroll
  for (int g = 0; g < 4; ++g)
#pragma unroll
    for (int j = 0; j < 8; ++j)
      if (r[g][j]) atomicOr(&gsh[(g * 64 + lane) * 8 + j], r[g][j]);
  __syncthreads();
  for (int i = tid; i < E_EDGES * 8; i += 512) {
    unsigned v = gsh[i];
    if (v) {
      // racy pre-read safe: gram freshly memset, OR monotone -> a stale 0
      // only costs an extra atomic; phase B re-reads at agent scope anyway.
      unsigned old = gram[i];
      if ((old | v) != old) atomicOr(&gram[i], v);
    }
  }

  // ---- overlap region (block-local work) before the spin ----
  {  // tile-0 U prestage
    const int blockRow0 = blockIdx.x * NPB;
    for (int i = tid; i < 64 * 32; i += 512) {
      const int row = i >> 5, c4 = i & 31;
      float4 vv = reinterpret_cast<const float4*>(U + (size_t)(blockRow0 + row) * IN_CH)[c4];
      __hip_bfloat16* dst = &A[row * 136 + c4 * 4];
      dst[0] = __float2bfloat16(vv.x);
      dst[1] = __float2bfloat16(vv.y);
      dst[2] = __float2bfloat16(vv.z);
      dst[3] = __float2bfloat16(vv.w);
    }
    if (tid < OUT_CH) bsh[tid] = bias[tid];
  }
  // MFMA B-fragments in registers from fp32 W. 8 waves x 32-col strips:
  // bfrag[nn][ks][j] = bf16(W[ks*32+quad*8+j][wave*32+nn*16+c16]).
  short8 bfrag[2][4];
#pragma unroll
  for (int nn = 0; nn < 2; ++nn) {
    const int col = wave * 32 + nn * 16 + c16;
#pragma unroll
    for (int ks = 0; ks < 4; ++ks) {
      short8 b;
#pragma unroll
      for (int j = 0; j < 8; ++j) {
        const float wv = W[(ks * 32 + quad * 8 + j) * OUT_CH + col];
        b[j] = (short)__builtin_bit_cast(unsigned short, __float2bfloat16(wv));
      }
      bfrag[nn][ks] = b;
    }
  }

  // ---- manual grid barrier (graph-capture-safe, proven in R3) ----
  __syncthreads();
  if (tid == 0) {
    int fb = 0;
    __hip_atomic_fetch_add(bar, 1u, __ATOMIC_ACQ_REL, __HIP_MEMORY_SCOPE_AGENT);
    unsigned spins = 0;
    while (__hip_atomic_load(bar, __ATOMIC_ACQUIRE, __HIP_MEMORY_SCOPE_AGENT) < NBLK) {
      __builtin_amdgcn_s_sleep(8);
      if (++spins > 2000000u) { fb = 1; break; }  // ~0.25 s >> legit ~100 us
    }
    fb_sh = fb;
  }
  __syncthreads();

  if (fb_sh) {
    // Fallback: co-residency broke. Recompute FULL gram locally (slow, correct).
    for (int i = tid; i < E_EDGES * 8; i += 512) gsh[i] = 0u;
    __syncthreads();
    unsigned r2[4][8];
#pragma unroll
    for (int g = 0; g < 4; ++g)
#pragma unroll
      for (int j = 0; j < 8; ++j) r2[g][j] = 0u;
    const int fn0 = wave * (N_NODES / 8);
    for (int it = 0; it < (N_NODES / 8) / 4; ++it) {
      const int n0 = fn0 + it * 4;
      float v[4][4];
#pragma unroll
      for (int q = 0; q < 4; ++q) {
        const float* row = H + (size_t)(n0 + q) * E_EDGES;
#pragma unroll
        for (int g = 0; g < 4; ++g) v[q][g] = row[lane + g * 64];
      }
#pragma unroll
      for (int q = 0; q < 4; ++q) {
        unsigned long long b0 = __ballot(v[q][0] >= 0.5f);
        unsigned long long b1 = __ballot(v[q][1] >= 0.5f);
        unsigned long long b2 = __ballot(v[q][2] >= 0.5f);
        unsigned long long b3 = __ballot(v[q][3] >= 0.5f);
        unsigned w[8] = {(unsigned)b0, (unsigned)(b0 >> 32),
                         (unsigned)b1, (unsigned)(b1 >> 32),
                         (unsigned)b2, (unsigned)(b2 >> 32),
                         (unsigned)b3, (unsigned)(b3 >> 32)};
        const unsigned long long bb[4] = {b0, b1, b2, b3};
#pragma unroll
        for (int g = 0; g < 4; ++g) {
          const unsigned sel = ((unsigned)(bb[g] >> lane) & 1u) ? 0xFFFFFFFFu : 0u;
#pragma unroll
          for (int j = 0; j < 8; ++j) r2[g][j] |= w[j] & sel;
        }
      }
    }
#pragma unroll
    for (int g = 0; g < 4; ++g)
#pragma unroll
      for (int j = 0; j < 8; ++j)
        if (r2[g][j]) atomicOr(&gsh[(g * 64 + lane) * 8 + j], r2[g][j]);
    __syncthreads();
  } else {
    // Re-read merged gram at the coherent point (agent scope).
    for (int i = tid; i < E_EDGES * 8; i += 512)
      gsh[i] = __hip_atomic_load(&gram[i], __ATOMIC_RELAXED, __HIP_MEMORY_SCOPE_AGENT);
  }

  // ---- phase B: 4 tiles of {64 rows x 256 cols, K=128}, 8 waves/tile ----
  for (int t = 0; t < TPB; ++t) {
    const int blockRow = blockIdx.x * NPB + t * 64;

    if (t > 0) {  // tile 0 staged before the barrier
      for (int i = tid; i < 64 * 32; i += 512) {
        const int row = i >> 5, c4 = i & 31;
        float4 vv = reinterpret_cast<const float4*>(U + (size_t)(blockRow + row) * IN_CH)[c4];
        __hip_bfloat16* dst = &A[row * 136 + c4 * 4];
        dst[0] = __float2bfloat16(vv.x);
        dst[1] = __float2bfloat16(vv.y);
        dst[2] = __float2bfloat16(vv.z);
        dst[3] = __float2bfloat16(vv.w);
      }
    }
    __syncthreads();  // A staged; ssh from prev tile fully consumed

    // wave 0: per-row scale (reads msh/gsh) while other waves MFMA
    if (tid < 64) {
      const int ln = t * 64 + tid;
      const unsigned long long m0 = msh[ln * 4 + 0];
      const unsigned long long m1 = msh[ln * 4 + 1];
      const unsigned long long m2 = msh[ln * 4 + 2];
      const unsigned long long m3 = msh[ln * 4 + 3];
      int dv = __popcll(m0) + __popcll(m1) + __popcll(m2) + __popcll(m3);
      unsigned o0 = 0, o1 = 0, o2 = 0, o3 = 0, o4 = 0, o5 = 0, o6 = 0, o7 = 0;
      auto scan = [&](unsigned long long bits, int g) {
        while (bits) {
          int tz = __builtin_ctzll(bits);
          bits &= bits - 1;
          const unsigned* gr = &gsh[((g << 6) + tz) * 8];
          o0 |= gr[0]; o1 |= gr[1]; o2 |= gr[2]; o3 |= gr[3];
          o4 |= gr[4]; o5 |= gr[5]; o6 |= gr[6]; o7 |= gr[7];
        }
      };
      scan(m0, 0); scan(m1, 1); scan(m2, 2); scan(m3, 3);
      dv += __popc(o0) + __popc(o1) + __popc(o2) + __popc(o3) +
            __popc(o4) + __popc(o5) + __popc(o6) + __popc(o7);
      float sv = 1.0f;
      if (dv > 0) sv += 1.0f / sqrtf((float)dv);
      ssh[tid] = sv;
    }

    float4v acc[4][2];
#pragma unroll
    for (int m = 0; m < 4; ++m)
#pragma unroll
      for (int nn = 0; nn < 2; ++nn)
        acc[m][nn] = (float4v){0.f, 0.f, 0.f, 0.f};

#pragma unroll
    for (int ks = 0; ks < 4; ++ks) {
      short8 a[4];
#pragma unroll
      for (int m = 0; m < 4; ++m)
        a[m] = *reinterpret_cast<const short8*>(&A[(m * 16 + c16) * 136 + ks * 32 + quad * 8]);
#pragma unroll
      for (int m = 0; m < 4; ++m)
#pragma unroll
        for (int nn = 0; nn < 2; ++nn)
          acc[m][nn] = __builtin_amdgcn_mfma_f32_16x16x32_bf16(a[m], bfrag[nn][ks], acc[m][nn], 0, 0, 0);
    }

    __syncthreads();  // ssh ready + A consumed (safe to restage next tile)

    // epilogue: C/D layout col = lane&15, row = quad*4 + reg
#pragma unroll
    for (int m = 0; m < 4; ++m) {
#pragma unroll
      for (int nn = 0; nn < 2; ++nn) {
        const int col = wave * 32 + nn * 16 + c16;
        const float bv = bsh[col];
#pragma unroll
        for (int rr = 0; rr < 4; ++rr) {
          const int row = m * 16 + quad * 4 + rr;
          out[(size_t)(blockRow + row) * OUT_CH + col] = ssh[row] * acc[m][nn][rr] + bv;
        }
      }
    }
  }
}

// ---------------------------------------------------------------------------
extern "C" void kernel_launch(void* const* d_in, const int* in_sizes, int n_in,
                              void* d_out, int out_size, void* d_ws, size_t ws_size,
                              hipStream_t stream) {
  const float* H    = (const float*)d_in[0];
  const float* U    = (const float*)d_in[1];
  const float* W    = (const float*)d_in[2];
  const float* bias = (const float*)d_in[3];
  float* out = (float*)d_out;

  // ws layout: gram bitmatrix (8 KiB) | barrier counter (cacheline)
  unsigned* gram = (unsigned*)d_ws;
  unsigned* bar  = (unsigned*)((char*)d_ws + 8192);

  hipMemsetAsync(d_ws, 0, 8192 + 64, stream);  // zero gram + barrier counter

  k_fused<<<dim3(NBLK), dim3(512), 0, stream>>>(H, U, W, bias, gram, bar, out);
}

// Round 5
// 299.907 us; speedup vs baseline: 1.3022x; 1.3022x over previous
//
#include <hip/hip_runtime.h>
#include <hip/hip_bf16.h>

typedef __attribute__((ext_vector_type(8))) short short8;
typedef __attribute__((ext_vector_type(4))) float float4v;

#define N_NODES 131072
#define E_EDGES 256
#define IN_CH   128
#define OUT_CH  256

// ---------------------------------------------------------------------------
// k1: per-node 256-bit incidence masks + gram nonzero-pattern bitmatrix.
// (verbatim from the verified 302.5us baseline -- R3/R4 fused variants were
// 80-90us slower kernel-side: global-barrier serialization + spin traffic,
// not occupancy, was the cost. Two-kernel structure restored.)
// ---------------------------------------------------------------------------
__global__ __launch_bounds__(512) void k_gram(const float* __restrict__ H,
                                              const float* __restrict__ W,
                                              unsigned long long* __restrict__ masks,
                                              unsigned* __restrict__ gram,
                                              __hip_bfloat16* __restrict__ Wb) {
  if (blockIdx.x == 256) {  // weight-conversion block
    for (int i = threadIdx.x; i < IN_CH * OUT_CH; i += 512) {
      const int f = i >> 9, lane = (i >> 3) & 63, j = i & 7;
      const int col = (f >> 2) * 16 + (lane & 15);
      const int k = (f & 3) * 32 + (lane >> 4) * 8 + j;
      Wb[i] = __float2bfloat16(W[k * OUT_CH + col]);
    }
    return;
  }

  const int wave = threadIdx.x >> 6;   // 0..7
  const int lane = threadIdx.x & 63;
  const int base = (blockIdx.x * 8 + wave) * 64;  // 64 nodes per wave

  unsigned r[4][8];
#pragma unroll
  for (int g = 0; g < 4; ++g)
#pragma unroll
    for (int j = 0; j < 8; ++j) r[g][j] = 0u;

  for (int it = 0; it < 16; ++it) {    // 4 nodes/iter -> 16 loads in flight
    const int n0 = base + it * 4;
    float v[4][4];
#pragma unroll
    for (int q = 0; q < 4; ++q) {
      const float* row = H + (size_t)(n0 + q) * E_EDGES;
#pragma unroll
      for (int g = 0; g < 4; ++g) v[q][g] = row[lane + g * 64];
    }
#pragma unroll
    for (int q = 0; q < 4; ++q) {
      unsigned long long b0 = __ballot(v[q][0] >= 0.5f);
      unsigned long long b1 = __ballot(v[q][1] >= 0.5f);
      unsigned long long b2 = __ballot(v[q][2] >= 0.5f);
      unsigned long long b3 = __ballot(v[q][3] >= 0.5f);
      if (lane < 4)
        masks[(size_t)(n0 + q) * 4 + lane] =
            (lane == 0) ? b0 : (lane == 1) ? b1 : (lane == 2) ? b2 : b3;
      unsigned w[8] = {(unsigned)b0, (unsigned)(b0 >> 32),
                       (unsigned)b1, (unsigned)(b1 >> 32),
                       (unsigned)b2, (unsigned)(b2 >> 32),
                       (unsigned)b3, (unsigned)(b3 >> 32)};
      const unsigned long long bb[4] = {b0, b1, b2, b3};
#pragma unroll
      for (int g = 0; g < 4; ++g) {
        const unsigned sel = ((unsigned)(bb[g] >> lane) & 1u) ? 0xFFFFFFFFu : 0u;
#pragma unroll
        for (int j = 0; j < 8; ++j) r[g][j] |= w[j] & sel;
      }
    }
  }

  __shared__ unsigned gsh[E_EDGES * 8];
  for (int i = threadIdx.x; i < E_EDGES * 8; i += 512) gsh[i] = 0u;
  __syncthreads();
#pragma unroll
  for (int g = 0; g < 4; ++g)
#pragma unroll
    for (int j = 0; j < 8; ++j)
      if (r[g][j]) atomicOr(&gsh[(g * 64 + lane) * 8 + j], r[g][j]);
  __syncthreads();
  for (int i = threadIdx.x; i < E_EDGES * 8; i += 512) {
    unsigned v = gsh[i];
    if (v) {
      // racy pre-read is safe: OR is monotone, stale read only costs an atomic
      unsigned old = gram[i];
      if ((old | v) != old) atomicOr(&gram[i], v);
    }
  }
}

// ---------------------------------------------------------------------------
// k2: fused scale+GEMM, now 128 rows x 256 cols per block (1024 blocks x
// 512 threads = 8 waves: 2 row-halves x 4 col-strips). Halves per-block
// fixed costs vs the 64-row baseline (gram/mask staging, block count,
// syncs per output byte) at identical 16-waves/CU occupancy (VGPR ~120,
// global-Wb fragment loads as before). Scan waves 0 and 4 compute
// s[row] = 1 + rsqrt(dv) for their 64-row half while other waves MFMA;
// scan has a saturation early-exit (gram rows are near-all-ones at this
// density -> ~1-2 iterations instead of ~13).
// ---------------------------------------------------------------------------
__global__ __launch_bounds__(512) void k_gemm(const float* __restrict__ U,
                                              const __hip_bfloat16* __restrict__ Wb,
                                              const unsigned long long* __restrict__ masks,
                                              const unsigned* __restrict__ gram,
                                              const float* __restrict__ bias,
                                              float* __restrict__ out) {
  __shared__ __hip_bfloat16 A[128 * 136];       // 34816 B (136: bank de-alias)
  __shared__ unsigned gsh[E_EDGES * 8];         //  8192 B
  __shared__ unsigned long long msh[128 * 4];   //  4096 B
  __shared__ float ssh[128];
  __shared__ float bsh[OUT_CH];

  const int tid = threadIdx.x;
  const int blockRow = blockIdx.x * 128;

  // stage U tile (128 x 128 fp32) -> bf16 LDS, coalesced float4
  for (int i = tid; i < 128 * 32; i += 512) {
    const int row = i >> 5, c4 = i & 31;
    float4 v = reinterpret_cast<const float4*>(U + (size_t)(blockRow + row) * IN_CH)[c4];
    __hip_bfloat16* dst = &A[row * 136 + c4 * 4];
    dst[0] = __float2bfloat16(v.x);
    dst[1] = __float2bfloat16(v.y);
    dst[2] = __float2bfloat16(v.z);
    dst[3] = __float2bfloat16(v.w);
  }
  // stage gram (512 uint4) + this block's 128 node masks (256 uint4)
  {
    uint4* g4 = reinterpret_cast<uint4*>(gsh);
    const uint4* src = reinterpret_cast<const uint4*>(gram);
    g4[tid] = src[tid];  // 512 threads x 16B = 8192 B exactly
    if (tid < 256) {
      reinterpret_cast<uint4*>(msh)[tid] =
          reinterpret_cast<const uint4*>(masks + (size_t)blockRow * 4)[tid];
      bsh[tid] = bias[tid];
    }
  }
  __syncthreads();

  const int wave = tid >> 6, lane = tid & 63;
  const int quad = lane >> 4, c16 = lane & 15;
  const int wr = wave >> 2, wc = wave & 3;   // row-half, col-strip

  // waves 0 and 4: per-row scale for their 64-row half while others MFMA
  if ((wave & 3) == 0) {
    const int ln = wr * 64 + lane;
    const unsigned long long m0 = msh[ln * 4 + 0];
    const unsigned long long m1 = msh[ln * 4 + 1];
    const unsigned long long m2 = msh[ln * 4 + 2];
    const unsigned long long m3 = msh[ln * 4 + 3];
    int dv = __popcll(m0) + __popcll(m1) + __popcll(m2) + __popcll(m3);
    unsigned o0 = 0, o1 = 0, o2 = 0, o3 = 0, o4 = 0, o5 = 0, o6 = 0, o7 = 0;
    auto scan = [&](unsigned long long bits, int g) -> bool {
      while (bits) {
        int t = __builtin_ctzll(bits);
        bits &= bits - 1;
        const unsigned* gr = &gsh[((g << 6) + t) * 8];
        o0 |= gr[0]; o1 |= gr[1]; o2 |= gr[2]; o3 |= gr[3];
        o4 |= gr[4]; o5 |= gr[5]; o6 |= gr[6]; o7 |= gr[7];
        // saturation early-exit: once the union is all-ones it can't grow
        if ((o0 & o1 & o2 & o3 & o4 & o5 & o6 & o7) == 0xFFFFFFFFu) return true;
      }
      return false;
    };
    (void)(scan(m0, 0) || scan(m1, 1) || scan(m2, 2) || scan(m3, 3));
    dv += __popc(o0) + __popc(o1) + __popc(o2) + __popc(o3) +
          __popc(o4) + __popc(o5) + __popc(o6) + __popc(o7);
    float sv = 1.0f;
    if (dv > 0) sv += 1.0f / sqrtf((float)dv);
    ssh[ln] = sv;
  }

  float4v acc[4][4];
#pragma unroll
  for (int m = 0; m < 4; ++m)
#pragma unroll
    for (int nn = 0; nn < 4; ++nn)
      acc[m][nn] = (float4v){0.f, 0.f, 0.f, 0.f};

#pragma unroll
  for (int ks = 0; ks < 4; ++ks) {
    short8 a[4], b[4];
#pragma unroll
    for (int m = 0; m < 4; ++m)
      a[m] = *reinterpret_cast<const short8*>(
          &A[(wr * 64 + m * 16 + c16) * 136 + ks * 32 + quad * 8]);
#pragma unroll
    for (int nn = 0; nn < 4; ++nn)
      b[nn] = *reinterpret_cast<const short8*>(
          Wb + ((size_t)(((wc * 4 + nn) * 4 + ks) * 64 + lane)) * 8);
#pragma unroll
    for (int m = 0; m < 4; ++m)
#pragma unroll
      for (int nn = 0; nn < 4; ++nn)
        acc[m][nn] = __builtin_amdgcn_mfma_f32_16x16x32_bf16(a[m], b[nn], acc[m][nn], 0, 0, 0);
  }

  __syncthreads();  // ssh ready for all waves

  // epilogue: C/D layout col = lane&15, row = quad*4 + reg
#pragma unroll
  for (int m = 0; m < 4; ++m) {
#pragma unroll
    for (int nn = 0; nn < 4; ++nn) {
      const int col = wc * 64 + nn * 16 + c16;
      const float bv = bsh[col];
#pragma unroll
      for (int rr = 0; rr < 4; ++rr) {
        const int row = wr * 64 + m * 16 + quad * 4 + rr;
        out[(size_t)(blockRow + row) * OUT_CH + col] = ssh[row] * acc[m][nn][rr] + bv;
      }
    }
  }
}

// ---------------------------------------------------------------------------
extern "C" void kernel_launch(void* const* d_in, const int* in_sizes, int n_in,
                              void* d_out, int out_size, void* d_ws, size_t ws_size,
                              hipStream_t stream) {
  const float* H    = (const float*)d_in[0];
  const float* U    = (const float*)d_in[1];
  const float* W    = (const float*)d_in[2];
  const float* bias = (const float*)d_in[3];
  float* out = (float*)d_out;

  // ws layout: gram bitmatrix (8 KiB) | masks (4 MiB) | Wb (64 KiB)
  char* ws = (char*)d_ws;
  unsigned* gram = (unsigned*)ws;
  unsigned long long* masks = (unsigned long long*)(ws + 8192);
  __hip_bfloat16* Wb = (__hip_bfloat16*)(ws + 8192 + (size_t)N_NODES * 32);

  hipMemsetAsync(gram, 0, E_EDGES * 8 * sizeof(unsigned), stream);
  k_gram<<<dim3(257), dim3(512), 0, stream>>>(H, W, masks, gram, Wb);
  k_gemm<<<dim3(N_NODES / 128), dim3(512), 0, stream>>>(U, Wb, masks, gram, bias, out);
}